// Round 11
// baseline (342.004 us; speedup 1.0000x reference)
//
#include <hip/hip_runtime.h>
#include <math.h>

#define B_TOTAL 16384
#define T_STEPS 20
#define NGRP    1024            // B_TOTAL/16 batch groups per sensor

typedef __attribute__((ext_vector_type(8))) __bf16 bf16x8;
typedef __attribute__((ext_vector_type(4))) float f32x4;

#define LOG2E_F 1.4426950408889634f
#define K2_F    2.8853900817779268f   // 2*log2(e)

// ---------------------------------------------------------------------------
__device__ __forceinline__ float exp2_fast(float x) {
#if __has_builtin(__builtin_amdgcn_exp2f)
    return __builtin_amdgcn_exp2f(x);       // bare v_exp_f32 (2^x)
#else
    return __expf(x * 0.6931471805599453f); // fallback: exp(ln2*x)
#endif
}

__device__ __forceinline__ __bf16 bf16_bits(unsigned short s) {
    __bf16 r; __builtin_memcpy(&r, &s, 2); return r;
}
// Truncation-based Dekker split (unchanged numerics).
__device__ __forceinline__ void split_trunc(float x, __bf16& hi, __bf16& lo) {
    unsigned u = __float_as_uint(x);
    hi = bf16_bits((unsigned short)(u >> 16));
    float l = x - __uint_as_float(u & 0xFFFF0000u);
    lo = bf16_bits((unsigned short)(__float_as_uint(l) >> 16));
}

// Fused LSTM cell activation in the exp2 domain (pre-scaled weights/biases):
//   c' = [c*(1+A)(1+C) + (C-1)(1+B)] / [(1+A)(1+B)(1+C)]
//   h  = (E-1) / ((1+D)(1+E))
__device__ __forceinline__ float lstm_act2(f32x4 a, float& c) {
    float eA = exp2_fast(-a[0]);
    float eB = exp2_fast(-a[1]);
    float eC = exp2_fast(a[2]);
    float aA = 1.0f + eA, aB = 1.0f + eB, aC = 1.0f + eC;
    float pAC = aA * aC;
    float r1  = __builtin_amdgcn_rcpf(pAC * aB);
    c = fmaf(c, pAC, (eC - 1.0f) * aB) * r1;
    float eD = exp2_fast(-a[3]);
    float eE = exp2_fast(K2_F * c);
    float r2 = __builtin_amdgcn_rcpf((1.0f + eD) * (1.0f + eE));
    return (eE - 1.0f) * r2;
}

// ---------------------------------------------------------------------------
// R11 = R10's lstm5 with the fc1 tail ABSORBED into layer 4's step loop:
// STEP_L(t) at layer 4 already loads bh/bl = slab t-1 for the hh projection,
// which is exactly the fc1 B-fragment for K-slice t-1. So the fc1 partial
// accumulates in-loop (3 extra MFMAs reusing bh/bl, 2 W1-frag L2 loads per
// step hidden by TLP); a small post-loop block handles t=19. The standalone
// serial tail (60 MFMAs + 40 L2 loads + 40 LDS reads per wave, previously
// exposed at block end) disappears. acc_fc chain order t=0..19 ascending
// with identical operand/MFMA order -> bit-identical partials.
__global__ __launch_bounds__(512, 8)
void lstm5_mfma(const float* __restrict__ accel, const float* __restrict__ gyro,
                const float* __restrict__ aWih0, const float* __restrict__ aWihR,
                const float* __restrict__ aWhh,  const float* __restrict__ aBih,
                const float* __restrict__ aBhh,
                const float* __restrict__ gWih0, const float* __restrict__ gWihR,
                const float* __restrict__ gWhh,  const float* __restrict__ gBih,
                const float* __restrict__ gBhh,
                const __bf16* __restrict__ w1ah, const __bf16* __restrict__ w1al,
                float* __restrict__ partial) {
    const int tid  = threadIdx.x;
    const int w    = tid >> 6;        // wave 0..7
    const int lane = tid & 63;
    const int e    = lane & 15;       // batch col within group
    const int quad = lane >> 4;       // 0..3
    const int sensor = blockIdx.y;
    const int bbase  = blockIdx.x * 16;

    const float* xin  = sensor ? gyro  : accel;
    const float* Wih0 = sensor ? gWih0 : aWih0;
    const float* WihR = sensor ? gWihR : aWihR;
    const float* Whh  = sensor ? gWhh  : aWhh;
    const float* Bih  = sensor ? gBih  : aBih;
    const float* Bhh  = sensor ? gBhh  : aBhh;

    __shared__ __align__(16) __bf16 shi[T_STEPS * 512];   // 20 KB
    __shared__ __align__(16) __bf16 slo[T_STEPS * 512];   // 20 KB -> 40960 total

    const int ug  = w * 4 + quad;        // this thread's hidden unit (0..31)
    const int swz = (e >> 1) & 3;

    // write index (bf16 units within a slab)
    const int widx = (e * 16 + ((w * 2 + (quad >> 1)) ^ (swz << 2))) * 2 + (quad & 1);
    // read base (bf16 units): 8 bf16 = units quad*8..quad*8+7 for col e
    const int rb_base = e * 32 + ((quad ^ swz) << 3);

    const int m_row = lane & 15;
    const int orow  = (m_row & 3) * 32 + (w * 4 + (m_row >> 2));
    // exp2-domain row scale: gate g (index 2) gets 2*log2e, others log2e
    const float wscale = ((m_row & 3) == 2) ? K2_F : LOG2E_F;

    bf16x8 wih_h, wih_l, whh_h, whh_l;
    bf16x8 ih_h, ih_l;                   // prefetched ih fragment
    f32x4  biasv;
    float  c0 = 0.f;

    // fc1 fusion state (layer 4 only)
    const __bf16* Wh1 = w1ah + ((size_t)(w * 40 + sensor * 20) * 64 + lane) * 8;
    const __bf16* Wl1 = w1al + ((size_t)(w * 40 + sensor * 20) * 64 + lane) * 8;
    f32x4 accf = (f32x4){0.f, 0.f, 0.f, 0.f};

// A-frag natural column order, prescaled: slot jj = wscale*W[row][quad*8+jj]
#define LOAD_FRAG(Wsrc, fh, fl)                               \
    {                                                         \
        const float* p_ = (Wsrc) + (orow) * 32 + quad * 8;    \
        _Pragma("unroll")                                     \
        for (int jj = 0; jj < 8; ++jj) {                      \
            __bf16 h_, l_;                                    \
            split_trunc(p_[jj] * wscale, h_, l_);             \
            (fh)[jj] = h_;  (fl)[jj] = l_;                    \
        }                                                     \
    }

#define LOAD_BIAS(l)                                                        \
    {                                                                       \
        _Pragma("unroll")                                                   \
        for (int r = 0; r < 4; ++r) {                                       \
            float bs_ = (r == 2) ? K2_F : LOG2E_F;                          \
            biasv[r] = (Bih[(l) * 128 + r * 32 + ug] +                      \
                        Bhh[(l) * 128 + r * 32 + ug]) * bs_;                \
        }                                                                   \
    }

    // ================= layer 0 (ih is K=3, done in VALU) =================
    {
        LOAD_FRAG(Whh, whh_h, whh_l);
        LOAD_BIAS(0);
        float w0reg[4][3];
#pragma unroll
        for (int r = 0; r < 4; ++r) {
            float bs_ = (r == 2) ? K2_F : LOG2E_F;
#pragma unroll
            for (int k = 0; k < 3; ++k)
                w0reg[r][k] = Wih0[(r * 32 + ug) * 3 + k] * bs_;
        }
        const float* xrow = xin + (size_t)(bbase + e) * (T_STEPS * 3);

#pragma unroll
        for (int t = 0; t < T_STEPS; ++t) {
            float x0 = xrow[t * 3 + 0];
            float x1 = xrow[t * 3 + 1];
            float x2 = xrow[t * 3 + 2];
            f32x4 acc = biasv;
#pragma unroll
            for (int r = 0; r < 4; ++r)
                acc[r] = fmaf(w0reg[r][0], x0,
                         fmaf(w0reg[r][1], x1,
                         fmaf(w0reg[r][2], x2, acc[r])));
            if (t > 0) {
                int rb = (t - 1) * 512 + rb_base;
                bf16x8 bh = *(const bf16x8*)&shi[rb];
                bf16x8 bl = *(const bf16x8*)&slo[rb];
                acc = __builtin_amdgcn_mfma_f32_16x16x32_bf16(whh_h, bh, acc, 0, 0, 0);
                acc = __builtin_amdgcn_mfma_f32_16x16x32_bf16(whh_h, bl, acc, 0, 0, 0);
                acc = __builtin_amdgcn_mfma_f32_16x16x32_bf16(whh_l, bh, acc, 0, 0, 0);
            }
            float h0 = lstm_act2(acc, c0);
            __bf16 hh_, ll_;
            split_trunc(h0, hh_, ll_);
            shi[t * 512 + widx] = hh_;
            slo[t * 512 + widx] = ll_;
            __syncthreads();              // write(t) -> next step's hh read
        }
    }

// -------- fully-unrolled MFMA-layer step (t compile-time; FC1 = fuse fc1
// accumulation for K-slice t-1, reusing this step's bh/bl LDS reads) --------
#define STEP_L(t, FC1)                                                      \
    {                                                                       \
        bf16x8 bh, bl, pf_h, pf_l;                                          \
        if ((t) > 0) {                                                      \
            bh = *(const bf16x8*)&shi[((t) - 1) * 512 + rb_base];           \
            bl = *(const bf16x8*)&slo[((t) - 1) * 512 + rb_base];           \
        }                                                                   \
        if ((t) < T_STEPS - 1) {      /* prefetch next step's ih */         \
            pf_h = *(const bf16x8*)&shi[((t) + 1) * 512 + rb_base];         \
            pf_l = *(const bf16x8*)&slo[((t) + 1) * 512 + rb_base];         \
        }                                                                   \
        f32x4 acc;                                                          \
        acc = __builtin_amdgcn_mfma_f32_16x16x32_bf16(wih_h, ih_h, biasv, 0, 0, 0); \
        acc = __builtin_amdgcn_mfma_f32_16x16x32_bf16(wih_h, ih_l, acc, 0, 0, 0);   \
        acc = __builtin_amdgcn_mfma_f32_16x16x32_bf16(wih_l, ih_h, acc, 0, 0, 0);   \
        if ((t) > 0) {                                                      \
            acc = __builtin_amdgcn_mfma_f32_16x16x32_bf16(whh_h, bh, acc, 0, 0, 0); \
            acc = __builtin_amdgcn_mfma_f32_16x16x32_bf16(whh_h, bl, acc, 0, 0, 0); \
            acc = __builtin_amdgcn_mfma_f32_16x16x32_bf16(whh_l, bh, acc, 0, 0, 0); \
            if (FC1) {                /* fc1 K-slice t-1: reuse bh/bl */    \
                bf16x8 ah = *(const bf16x8*)(Wh1 + (size_t)((t) - 1) * 512);\
                bf16x8 av = *(const bf16x8*)(Wl1 + (size_t)((t) - 1) * 512);\
                accf = __builtin_amdgcn_mfma_f32_16x16x32_bf16(ah, bh, accf, 0, 0, 0); \
                accf = __builtin_amdgcn_mfma_f32_16x16x32_bf16(ah, bl, accf, 0, 0, 0); \
                accf = __builtin_amdgcn_mfma_f32_16x16x32_bf16(av, bh, accf, 0, 0, 0); \
            }                                                               \
        }                                                                   \
        float h0 = lstm_act2(acc, c0);                                      \
        __bf16 hh_, ll_;                                                    \
        split_trunc(h0, hh_, ll_);                                          \
        shi[(t) * 512 + widx] = hh_;                                        \
        slo[(t) * 512 + widx] = ll_;                                        \
        if ((t) < T_STEPS - 1) { ih_h = pf_h; ih_l = pf_l; }                \
        __syncthreads();              /* write(t) -> next step's reads */   \
    }

    // ================= layers 1..4 (both projections via MFMA) ===========
    for (int l = 1; l < 5; ++l) {
        const float* Wi = WihR + (l - 1) * 4096;
        const float* Wh = Whh + l * 4096;
        LOAD_FRAG(Wi, wih_h, wih_l);
        LOAD_FRAG(Wh, whh_h, whh_l);
        LOAD_BIAS(l);
        c0 = 0.f;

        // prologue: prefetch ih(0) = h_{l-1}(0) from slab 0 (stable), then
        // barrier so no wave's t=0 write to slab 0 races another's read.
        ih_h = *(const bf16x8*)&shi[rb_base];
        ih_l = *(const bf16x8*)&slo[rb_base];
        __syncthreads();

        if (l < 4) {
#pragma unroll
            for (int t = 0; t < T_STEPS; ++t) STEP_L(t, 0);
        } else {
#pragma unroll
            for (int t = 0; t < T_STEPS; ++t) STEP_L(t, 1);
        }
    }
    // last STEP_L ended with __syncthreads(): all layer-4 slabs visible.

    // ---- fc1 epilogue: final K-slice t=19 (one read pair + 3 MFMAs) ----
    {
        bf16x8 bh = *(const bf16x8*)&shi[19 * 512 + rb_base];
        bf16x8 bl = *(const bf16x8*)&slo[19 * 512 + rb_base];
        bf16x8 ah = *(const bf16x8*)(Wh1 + (size_t)19 * 512);
        bf16x8 av = *(const bf16x8*)(Wl1 + (size_t)19 * 512);
        accf = __builtin_amdgcn_mfma_f32_16x16x32_bf16(ah, bh, accf, 0, 0, 0);
        accf = __builtin_amdgcn_mfma_f32_16x16x32_bf16(ah, bl, accf, 0, 0, 0);
        accf = __builtin_amdgcn_mfma_f32_16x16x32_bf16(av, bh, accf, 0, 0, 0);

        // partial[(sensor*NGRP+g)*8 + mt][e][rl]: C row = quad*4+r, col = e
        float4 v = make_float4(accf[0], accf[1], accf[2], accf[3]);
        *(float4*)(partial +
                   ((size_t)(sensor * NGRP + blockIdx.x) * 8 + w) * 256 +
                   e * 16 + quad * 4) = v;
    }
#undef LOAD_FRAG
#undef LOAD_BIAS
#undef STEP_L
}

// ---------------------------------------------------------------------------
// fc1_w [128][1280] -> MFMA A-frag hi/lo arrays: [mt 0..7][ks 0..39][lane][8]
// Natural column order (matches natural-unit B layout).
__global__ void w1_prep(const float* __restrict__ w1,
                        __bf16* __restrict__ w1ah, __bf16* __restrict__ w1al) {
    int t = blockIdx.x * blockDim.x + threadIdx.x;     // 8*40*64 = 20480
    if (t >= 20480) return;
    int lane = t & 63;
    int ks   = (t >> 6) % 40;
    int mt   = t / (64 * 40);
    int row  = mt * 16 + (lane & 15);
    int col0 = ks * 32 + (lane >> 4) * 8;
    const float* src = w1 + row * 1280 + col0;
#pragma unroll
    for (int j = 0; j < 8; ++j) {
        __bf16 h_, l_;
        split_trunc(src[j], h_, l_);
        w1ah[t * 8 + j] = h_;
        w1al[t * 8 + j] = l_;
    }
}

// ---------------------------------------------------------------------------
// fc2_combine: thread t loads floats [8t..8t+7] of each sensor's partial
// (fully coalesced), v = relu(zA+zB+fc1_b) for its 8 rows, fc2 dot-partials
// from LDS-staged fc2_w, then a 16-contributor LDS reduce per column.
__global__ __launch_bounds__(256, 4)
void fc2_combine(const float* __restrict__ partial,
                 const float* __restrict__ fc1_b, const float* __restrict__ fc2_w,
                 const float* __restrict__ fc2_b, float* __restrict__ out) {
    const int tid = threadIdx.x;
    const int g   = blockIdx.x;

    __shared__ float sw2[640];           // fc2_w [5][128]
    __shared__ float sb1[128];           // fc1_b
    __shared__ float sred[16][16][5];    // [col][contributor][n]

    for (int i = tid; i < 640; i += 256) sw2[i] = fc2_w[i];
    if (tid < 128) sb1[tid] = fc1_b[tid];
    __syncthreads();

    const float* pa = partial + (size_t)g * 2048 + tid * 8;
    const float* pb = partial + (size_t)(NGRP + g) * 2048 + tid * 8;
    float4 a0 = *(const float4*)(pa);
    float4 a1 = *(const float4*)(pa + 4);
    float4 b0 = *(const float4*)(pb);
    float4 b1 = *(const float4*)(pb + 4);
    float z[8] = {a0.x + b0.x, a0.y + b0.y, a0.z + b0.z, a0.w + b0.w,
                  a1.x + b1.x, a1.y + b1.y, a1.z + b1.z, a1.w + b1.w};

    const int mt   = tid >> 5;           // 0..7
    const int col  = (tid >> 1) & 15;
    const int row0 = mt * 16 + (tid & 1) * 8;
    float p[5] = {0.f, 0.f, 0.f, 0.f, 0.f};
#pragma unroll
    for (int j = 0; j < 8; ++j) {
        int row = row0 + j;
        float v = fmaxf(z[j] + sb1[row], 0.f);
#pragma unroll
        for (int n = 0; n < 5; ++n) p[n] = fmaf(v, sw2[n * 128 + row], p[n]);
    }
    const int c = mt * 2 + (tid & 1);    // contributor 0..15
#pragma unroll
    for (int n = 0; n < 5; ++n) sred[col][c][n] = p[n];
    __syncthreads();

    if (tid < 80) {
        int cl = tid / 5, n = tid - cl * 5;
        float s = fc2_b[n];
#pragma unroll
        for (int cc = 0; cc < 16; ++cc) s += sred[cl][cc][n];
        out[(size_t)(g * 16 + cl) * 5 + n] = s;
    }
}

// ---------------------------------------------------------------------------
extern "C" void kernel_launch(void* const* d_in, const int* in_sizes, int n_in,
                              void* d_out, int out_size, void* d_ws, size_t ws_size,
                              hipStream_t stream) {
    const float* accel  = (const float*)d_in[0];
    const float* gyro   = (const float*)d_in[1];
    const float* aWih0  = (const float*)d_in[2];
    const float* aWihR  = (const float*)d_in[3];
    const float* aWhh   = (const float*)d_in[4];
    const float* aBih   = (const float*)d_in[5];
    const float* aBhh   = (const float*)d_in[6];
    const float* gWih0  = (const float*)d_in[7];
    const float* gWihR  = (const float*)d_in[8];
    const float* gWhh   = (const float*)d_in[9];
    const float* gBih   = (const float*)d_in[10];
    const float* gBhh   = (const float*)d_in[11];
    const float* fc1_w  = (const float*)d_in[12];
    const float* fc1_b  = (const float*)d_in[13];
    const float* fc2_w  = (const float*)d_in[14];
    const float* fc2_b  = (const float*)d_in[15];
    float* out = (float*)d_out;

    // workspace: W1 frag arrays (163840 bf16 each) + fc1 partials (16.8 MB)
    __bf16* W1ah = (__bf16*)d_ws;
    __bf16* W1al = W1ah + 163840;
    float*  Pacc = (float*)(W1al + 163840);   // 2*NGRP*8*256 f32

    hipLaunchKernelGGL(w1_prep, dim3(80), dim3(256), 0, stream, fc1_w, W1ah, W1al);

    hipLaunchKernelGGL(lstm5_mfma, dim3(NGRP, 2), dim3(512), 0, stream,
                       accel, gyro, aWih0, aWihR, aWhh, aBih, aBhh,
                       gWih0, gWihR, gWhh, gBih, gBhh, W1ah, W1al, Pacc);

    hipLaunchKernelGGL(fc2_combine, dim3(NGRP), dim3(256), 0, stream,
                       Pacc, fc1_b, fc2_w, fc2_b, out);
}

// Round 12
// 274.682 us; speedup vs baseline: 1.2451x; 1.2451x over previous
//
#include <hip/hip_runtime.h>
#include <math.h>

#define B_TOTAL 16384
#define T_STEPS 20
#define NGRP    1024            // B_TOTAL/16 batch groups per sensor

typedef __attribute__((ext_vector_type(8))) __bf16 bf16x8;
typedef __attribute__((ext_vector_type(4))) float f32x4;

#define LOG2E_F 1.4426950408889634f
#define K2_F    2.8853900817779268f   // 2*log2(e)

// ---------------------------------------------------------------------------
__device__ __forceinline__ float exp2_fast(float x) {
#if __has_builtin(__builtin_amdgcn_exp2f)
    return __builtin_amdgcn_exp2f(x);       // bare v_exp_f32 (2^x)
#else
    return __expf(x * 0.6931471805599453f); // fallback: exp(ln2*x)
#endif
}

__device__ __forceinline__ __bf16 bf16_bits(unsigned short s) {
    __bf16 r; __builtin_memcpy(&r, &s, 2); return r;
}
// Truncation-based Dekker split (unchanged numerics).
__device__ __forceinline__ void split_trunc(float x, __bf16& hi, __bf16& lo) {
    unsigned u = __float_as_uint(x);
    hi = bf16_bits((unsigned short)(u >> 16));
    float l = x - __uint_as_float(u & 0xFFFF0000u);
    lo = bf16_bits((unsigned short)(__float_as_uint(l) >> 16));
}

// Fused LSTM cell activation in the exp2 domain (pre-scaled weights/biases):
//   c' = [c*(1+A)(1+C) + (C-1)(1+B)] / [(1+A)(1+B)(1+C)]
//   h  = (E-1) / ((1+D)(1+E))
__device__ __forceinline__ float lstm_act2(f32x4 a, float& c) {
    float eA = exp2_fast(-a[0]);
    float eB = exp2_fast(-a[1]);
    float eC = exp2_fast(a[2]);
    float aA = 1.0f + eA, aB = 1.0f + eB, aC = 1.0f + eC;
    float pAC = aA * aC;
    float r1  = __builtin_amdgcn_rcpf(pAC * aB);
    c = fmaf(c, pAC, (eC - 1.0f) * aB) * r1;
    float eD = exp2_fast(-a[3]);
    float eE = exp2_fast(K2_F * c);
    float r2 = __builtin_amdgcn_rcpf((1.0f + eD) * (1.0f + eE));
    return (eE - 1.0f) * r2;
}

// ---------------------------------------------------------------------------
// R12 = R10 verbatim (measured best: lstm5 204 us, e2e 278.1 us).
// R11's in-loop fc1 fusion spilled (FETCH 246 GB of scratch traffic) — at
// the 512-thread/8-wave point the register budget is exactly consumed by
// this loop body; all structural additions (R8 mono-kernel, R9 on-the-fly
// split, R11 in-loop fc1) spill and regress. lstm5 here is issue-saturated
// (VALUBusy 64 + MfmaUtil 35 ~ 99%) at 73% occupancy.
__global__ __launch_bounds__(512, 8)
void lstm5_mfma(const float* __restrict__ accel, const float* __restrict__ gyro,
                const float* __restrict__ aWih0, const float* __restrict__ aWihR,
                const float* __restrict__ aWhh,  const float* __restrict__ aBih,
                const float* __restrict__ aBhh,
                const float* __restrict__ gWih0, const float* __restrict__ gWihR,
                const float* __restrict__ gWhh,  const float* __restrict__ gBih,
                const float* __restrict__ gBhh,
                const __bf16* __restrict__ w1ah, const __bf16* __restrict__ w1al,
                float* __restrict__ partial) {
    const int tid  = threadIdx.x;
    const int w    = tid >> 6;        // wave 0..7
    const int lane = tid & 63;
    const int e    = lane & 15;       // batch col within group
    const int quad = lane >> 4;       // 0..3
    const int sensor = blockIdx.y;
    const int bbase  = blockIdx.x * 16;

    const float* xin  = sensor ? gyro  : accel;
    const float* Wih0 = sensor ? gWih0 : aWih0;
    const float* WihR = sensor ? gWihR : aWihR;
    const float* Whh  = sensor ? gWhh  : aWhh;
    const float* Bih  = sensor ? gBih  : aBih;
    const float* Bhh  = sensor ? gBhh  : aBhh;

    __shared__ __align__(16) __bf16 shi[T_STEPS * 512];   // 20 KB
    __shared__ __align__(16) __bf16 slo[T_STEPS * 512];   // 20 KB -> 40960 total

    const int ug  = w * 4 + quad;        // this thread's hidden unit (0..31)
    const int swz = (e >> 1) & 3;

    // write index (bf16 units within a slab)
    const int widx = (e * 16 + ((w * 2 + (quad >> 1)) ^ (swz << 2))) * 2 + (quad & 1);
    // read base (bf16 units): 8 bf16 = units quad*8..quad*8+7 for col e
    const int rb_base = e * 32 + ((quad ^ swz) << 3);

    const int m_row = lane & 15;
    const int orow  = (m_row & 3) * 32 + (w * 4 + (m_row >> 2));
    // exp2-domain row scale: gate g (index 2) gets 2*log2e, others log2e
    const float wscale = ((m_row & 3) == 2) ? K2_F : LOG2E_F;

    bf16x8 wih_h, wih_l, whh_h, whh_l;
    bf16x8 ih_h, ih_l;                   // prefetched ih fragment
    f32x4  biasv;
    float  c0 = 0.f;

// A-frag natural column order, prescaled: slot jj = wscale*W[row][quad*8+jj]
#define LOAD_FRAG(Wsrc, fh, fl)                               \
    {                                                         \
        const float* p_ = (Wsrc) + (orow) * 32 + quad * 8;    \
        _Pragma("unroll")                                     \
        for (int jj = 0; jj < 8; ++jj) {                      \
            __bf16 h_, l_;                                    \
            split_trunc(p_[jj] * wscale, h_, l_);             \
            (fh)[jj] = h_;  (fl)[jj] = l_;                    \
        }                                                     \
    }

#define LOAD_BIAS(l)                                                        \
    {                                                                       \
        _Pragma("unroll")                                                   \
        for (int r = 0; r < 4; ++r) {                                       \
            float bs_ = (r == 2) ? K2_F : LOG2E_F;                          \
            biasv[r] = (Bih[(l) * 128 + r * 32 + ug] +                      \
                        Bhh[(l) * 128 + r * 32 + ug]) * bs_;                \
        }                                                                   \
    }

    // ================= layer 0 (ih is K=3, done in VALU) =================
    {
        LOAD_FRAG(Whh, whh_h, whh_l);
        LOAD_BIAS(0);
        float w0reg[4][3];
#pragma unroll
        for (int r = 0; r < 4; ++r) {
            float bs_ = (r == 2) ? K2_F : LOG2E_F;
#pragma unroll
            for (int k = 0; k < 3; ++k)
                w0reg[r][k] = Wih0[(r * 32 + ug) * 3 + k] * bs_;
        }
        const float* xrow = xin + (size_t)(bbase + e) * (T_STEPS * 3);

#pragma unroll
        for (int t = 0; t < T_STEPS; ++t) {
            float x0 = xrow[t * 3 + 0];
            float x1 = xrow[t * 3 + 1];
            float x2 = xrow[t * 3 + 2];
            f32x4 acc = biasv;
#pragma unroll
            for (int r = 0; r < 4; ++r)
                acc[r] = fmaf(w0reg[r][0], x0,
                         fmaf(w0reg[r][1], x1,
                         fmaf(w0reg[r][2], x2, acc[r])));
            if (t > 0) {
                int rb = (t - 1) * 512 + rb_base;
                bf16x8 bh = *(const bf16x8*)&shi[rb];
                bf16x8 bl = *(const bf16x8*)&slo[rb];
                acc = __builtin_amdgcn_mfma_f32_16x16x32_bf16(whh_h, bh, acc, 0, 0, 0);
                acc = __builtin_amdgcn_mfma_f32_16x16x32_bf16(whh_h, bl, acc, 0, 0, 0);
                acc = __builtin_amdgcn_mfma_f32_16x16x32_bf16(whh_l, bh, acc, 0, 0, 0);
            }
            float h0 = lstm_act2(acc, c0);
            __bf16 hh_, ll_;
            split_trunc(h0, hh_, ll_);
            shi[t * 512 + widx] = hh_;
            slo[t * 512 + widx] = ll_;
            __syncthreads();              // write(t) -> next step's hh read
        }
    }

// -------- fully-unrolled MFMA-layer step (t is a compile-time constant) ----
#define STEP_L(t)                                                           \
    {                                                                       \
        bf16x8 bh, bl, pf_h, pf_l;                                          \
        if ((t) > 0) {                                                      \
            bh = *(const bf16x8*)&shi[((t) - 1) * 512 + rb_base];           \
            bl = *(const bf16x8*)&slo[((t) - 1) * 512 + rb_base];           \
        }                                                                   \
        if ((t) < T_STEPS - 1) {      /* prefetch next step's ih */         \
            pf_h = *(const bf16x8*)&shi[((t) + 1) * 512 + rb_base];         \
            pf_l = *(const bf16x8*)&slo[((t) + 1) * 512 + rb_base];         \
        }                                                                   \
        f32x4 acc;                                                          \
        acc = __builtin_amdgcn_mfma_f32_16x16x32_bf16(wih_h, ih_h, biasv, 0, 0, 0); \
        acc = __builtin_amdgcn_mfma_f32_16x16x32_bf16(wih_h, ih_l, acc, 0, 0, 0);   \
        acc = __builtin_amdgcn_mfma_f32_16x16x32_bf16(wih_l, ih_h, acc, 0, 0, 0);   \
        if ((t) > 0) {                                                      \
            acc = __builtin_amdgcn_mfma_f32_16x16x32_bf16(whh_h, bh, acc, 0, 0, 0); \
            acc = __builtin_amdgcn_mfma_f32_16x16x32_bf16(whh_h, bl, acc, 0, 0, 0); \
            acc = __builtin_amdgcn_mfma_f32_16x16x32_bf16(whh_l, bh, acc, 0, 0, 0); \
        }                                                                   \
        float h0 = lstm_act2(acc, c0);                                      \
        __bf16 hh_, ll_;                                                    \
        split_trunc(h0, hh_, ll_);                                          \
        shi[(t) * 512 + widx] = hh_;                                        \
        slo[(t) * 512 + widx] = ll_;                                        \
        if ((t) < T_STEPS - 1) { ih_h = pf_h; ih_l = pf_l; }                \
        __syncthreads();              /* write(t) -> next step's reads */   \
    }

    // ================= layers 1..4 (both projections via MFMA) ===========
    for (int l = 1; l < 5; ++l) {
        const float* Wi = WihR + (l - 1) * 4096;
        const float* Wh = Whh + l * 4096;
        LOAD_FRAG(Wi, wih_h, wih_l);
        LOAD_FRAG(Wh, whh_h, whh_l);
        LOAD_BIAS(l);
        c0 = 0.f;

        // prologue: prefetch ih(0) = h_{l-1}(0) from slab 0 (stable), then
        // barrier so no wave's t=0 write to slab 0 races another's read.
        ih_h = *(const bf16x8*)&shi[rb_base];
        ih_l = *(const bf16x8*)&slo[rb_base];
        __syncthreads();

#pragma unroll
        for (int t = 0; t < T_STEPS; ++t) STEP_L(t);
    }
    // last STEP_L ended with __syncthreads(): all layer-4 slabs visible.

    // ---- fused fc1 partial: wave w = m-tile w over this sensor's 20 ks ----
    // A-frags: w1ah/w1al at ks = sensor*20 + t (prepped layout); B-frags:
    // LDS slabs at rb_base. Bit-identical operands to the R7 tail.
    {
        const __bf16* Wh1 = w1ah + ((size_t)(w * 40 + sensor * 20) * 64 + lane) * 8;
        const __bf16* Wl1 = w1al + ((size_t)(w * 40 + sensor * 20) * 64 + lane) * 8;
        f32x4 acc = (f32x4){0.f, 0.f, 0.f, 0.f};
#pragma unroll
        for (int t = 0; t < T_STEPS; ++t) {
            bf16x8 bh = *(const bf16x8*)&shi[t * 512 + rb_base];
            bf16x8 bl = *(const bf16x8*)&slo[t * 512 + rb_base];
            bf16x8 ah = *(const bf16x8*)(Wh1 + (size_t)t * 512);
            bf16x8 av = *(const bf16x8*)(Wl1 + (size_t)t * 512);
            acc = __builtin_amdgcn_mfma_f32_16x16x32_bf16(ah, bh, acc, 0, 0, 0);
            acc = __builtin_amdgcn_mfma_f32_16x16x32_bf16(ah, bl, acc, 0, 0, 0);
            acc = __builtin_amdgcn_mfma_f32_16x16x32_bf16(av, bh, acc, 0, 0, 0);
        }
        // partial[(sensor*NGRP+g)*8 + mt][e][rl]: C row = quad*4+r, col = e
        float4 v = make_float4(acc[0], acc[1], acc[2], acc[3]);
        *(float4*)(partial +
                   ((size_t)(sensor * NGRP + blockIdx.x) * 8 + w) * 256 +
                   e * 16 + quad * 4) = v;
    }
#undef LOAD_FRAG
#undef LOAD_BIAS
#undef STEP_L
}

// ---------------------------------------------------------------------------
// fc1_w [128][1280] -> MFMA A-frag hi/lo arrays: [mt 0..7][ks 0..39][lane][8]
// Natural column order (matches natural-unit B layout).
__global__ void w1_prep(const float* __restrict__ w1,
                        __bf16* __restrict__ w1ah, __bf16* __restrict__ w1al) {
    int t = blockIdx.x * blockDim.x + threadIdx.x;     // 8*40*64 = 20480
    if (t >= 20480) return;
    int lane = t & 63;
    int ks   = (t >> 6) % 40;
    int mt   = t / (64 * 40);
    int row  = mt * 16 + (lane & 15);
    int col0 = ks * 32 + (lane >> 4) * 8;
    const float* src = w1 + row * 1280 + col0;
#pragma unroll
    for (int j = 0; j < 8; ++j) {
        __bf16 h_, l_;
        split_trunc(src[j], h_, l_);
        w1ah[t * 8 + j] = h_;
        w1al[t * 8 + j] = l_;
    }
}

// ---------------------------------------------------------------------------
// fc2_combine: thread t loads floats [8t..8t+7] of each sensor's partial
// (fully coalesced), v = relu(zA+zB+fc1_b) for its 8 rows, fc2 dot-partials
// from LDS-staged fc2_w, then a 16-contributor LDS reduce per column.
__global__ __launch_bounds__(256, 4)
void fc2_combine(const float* __restrict__ partial,
                 const float* __restrict__ fc1_b, const float* __restrict__ fc2_w,
                 const float* __restrict__ fc2_b, float* __restrict__ out) {
    const int tid = threadIdx.x;
    const int g   = blockIdx.x;

    __shared__ float sw2[640];           // fc2_w [5][128]
    __shared__ float sb1[128];           // fc1_b
    __shared__ float sred[16][16][5];    // [col][contributor][n]

    for (int i = tid; i < 640; i += 256) sw2[i] = fc2_w[i];
    if (tid < 128) sb1[tid] = fc1_b[tid];
    __syncthreads();

    const float* pa = partial + (size_t)g * 2048 + tid * 8;
    const float* pb = partial + (size_t)(NGRP + g) * 2048 + tid * 8;
    float4 a0 = *(const float4*)(pa);
    float4 a1 = *(const float4*)(pa + 4);
    float4 b0 = *(const float4*)(pb);
    float4 b1 = *(const float4*)(pb + 4);
    float z[8] = {a0.x + b0.x, a0.y + b0.y, a0.z + b0.z, a0.w + b0.w,
                  a1.x + b1.x, a1.y + b1.y, a1.z + b1.z, a1.w + b1.w};

    const int mt   = tid >> 5;           // 0..7
    const int col  = (tid >> 1) & 15;
    const int row0 = mt * 16 + (tid & 1) * 8;
    float p[5] = {0.f, 0.f, 0.f, 0.f, 0.f};
#pragma unroll
    for (int j = 0; j < 8; ++j) {
        int row = row0 + j;
        float v = fmaxf(z[j] + sb1[row], 0.f);
#pragma unroll
        for (int n = 0; n < 5; ++n) p[n] = fmaf(v, sw2[n * 128 + row], p[n]);
    }
    const int c = mt * 2 + (tid & 1);    // contributor 0..15
#pragma unroll
    for (int n = 0; n < 5; ++n) sred[col][c][n] = p[n];
    __syncthreads();

    if (tid < 80) {
        int cl = tid / 5, n = tid - cl * 5;
        float s = fc2_b[n];
#pragma unroll
        for (int cc = 0; cc < 16; ++cc) s += sred[cl][cc][n];
        out[(size_t)(g * 16 + cl) * 5 + n] = s;
    }
}

// ---------------------------------------------------------------------------
extern "C" void kernel_launch(void* const* d_in, const int* in_sizes, int n_in,
                              void* d_out, int out_size, void* d_ws, size_t ws_size,
                              hipStream_t stream) {
    const float* accel  = (const float*)d_in[0];
    const float* gyro   = (const float*)d_in[1];
    const float* aWih0  = (const float*)d_in[2];
    const float* aWihR  = (const float*)d_in[3];
    const float* aWhh   = (const float*)d_in[4];
    const float* aBih   = (const float*)d_in[5];
    const float* aBhh   = (const float*)d_in[6];
    const float* gWih0  = (const float*)d_in[7];
    const float* gWihR  = (const float*)d_in[8];
    const float* gWhh   = (const float*)d_in[9];
    const float* gBih   = (const float*)d_in[10];
    const float* gBhh   = (const float*)d_in[11];
    const float* fc1_w  = (const float*)d_in[12];
    const float* fc1_b  = (const float*)d_in[13];
    const float* fc2_w  = (const float*)d_in[14];
    const float* fc2_b  = (const float*)d_in[15];
    float* out = (float*)d_out;

    // workspace: W1 frag arrays (163840 bf16 each) + fc1 partials (16.8 MB)
    __bf16* W1ah = (__bf16*)d_ws;
    __bf16* W1al = W1ah + 163840;
    float*  Pacc = (float*)(W1al + 163840);   // 2*NGRP*8*256 f32

    hipLaunchKernelGGL(w1_prep, dim3(80), dim3(256), 0, stream, fc1_w, W1ah, W1al);

    hipLaunchKernelGGL(lstm5_mfma, dim3(NGRP, 2), dim3(512), 0, stream,
                       accel, gyro, aWih0, aWihR, aWhh, aBih, aBhh,
                       gWih0, gWihR, gWhh, gBih, gBhh, W1ah, W1al, Pacc);

    hipLaunchKernelGGL(fc2_combine, dim3(NGRP), dim3(256), 0, stream,
                       Pacc, fc1_b, fc2_w, fc2_b, out);
}